// Round 8
// baseline (133.739 us; speedup 1.0000x reference)
//
#include <hip/hip_runtime.h>

typedef short   bf16x8 __attribute__((ext_vector_type(8)));
typedef float   f32x4  __attribute__((ext_vector_type(4)));
typedef float   f32x2  __attribute__((ext_vector_type(2)));

#define NVEC   131072      // 32*64*64 vectors
#define HW     4096
#define CHW    262144
#define QOFF   1
#define PERPOFF 8388609
#define ENCOFF  8388610

// ws layout: counts[512] @0, double loss @2048, float bias[512] @4096,
//            ushort wbf[512*64] @8192 (64 KB)

__device__ inline unsigned short f2bf(float f) {   // RTNE float->bf16
    unsigned int u = __float_as_uint(f);
    u += 0x7fffu + ((u >> 16) & 1u);
    return (unsigned short)(u >> 16);
}

// per code: bf16 copy of W + bias = -0.5*||w||^2 (f32-exact).
// Block 0 additionally zeroes counts + loss.
__global__ __launch_bounds__(64) void vq_prep(const float* __restrict__ wt,
                                              float* __restrict__ bias,
                                              unsigned short* __restrict__ wbf,
                                              int* __restrict__ counts,
                                              double* __restrict__ loss) {
    int c = blockIdx.x, d = threadIdx.x;
    if (c == 0) {
#pragma unroll
        for (int i = 0; i < 8; ++i) counts[d * 8 + i] = 0;
        if (d == 0) loss[0] = 0.0;
    }
    float v = wt[c * 64 + d];
    wbf[c * 64 + d] = f2bf(v);
    float s = v * v;
    for (int off = 32; off; off >>= 1) s += __shfl_down(s, off, 64);
    if (d == 0) bias[c] = -0.5f * s;
}

// 512 blocks x 512 threads (8 waves), 2 blocks/CU (VGPR capped at 128).
// Wave handles 32 rows. Scores via mfma_f32_16x16x32_bf16 (C = -wsq/2);
// epilogue: quantized_st + loss + FULL one-hot rows (single-touch NT stores).
__global__ __launch_bounds__(512, 4) void vq_assign(
    const float* __restrict__ x, const float* __restrict__ wt,
    const float* __restrict__ bias, const unsigned short* __restrict__ wbf,
    float* __restrict__ out, int* __restrict__ counts,
    double* __restrict__ loss_acc)
{
    __shared__ unsigned short wl[512 * 64];   // 64 KB, XOR-swizzled rows
    __shared__ float  biasl[512];
    __shared__ int    hc[512];
    __shared__ int    winners[256];
    __shared__ double lred[8];

    const int t = threadIdx.x, b = blockIdx.x;
    const int batch  = b >> 4;
    const int posblk = (b & 15) << 8;

    // ---- stage W bf16 into LDS with st-swizzle (row c: byte ^= (c&7)<<4) ----
    {
        const ulonglong2* src = (const ulonglong2*)wbf;   // 16B units
#pragma unroll
        for (int i = 0; i < 8; ++i) {
            int u  = t + 512 * i;          // 16B-unit index, 0..4095
            int c  = u >> 3;               // code row
            int bo = (u & 7) << 4;         // byte-in-row
            ulonglong2 v = src[u];
            *(ulonglong2*)((char*)wl + ((c << 7) | (bo ^ ((c & 7) << 4)))) = v;
        }
        biasl[t] = bias[t];
        hc[t] = 0;
    }
    __syncthreads();

    const int wv = t >> 6, l = t & 63;
    const int g  = l >> 4, cl = l & 15;
    const int posw = posblk + (wv << 5);      // this wave's 32 pos
    const int d0 = g << 3;

    // ---- load X f32 directly in A-fragment layout ----
    float xs[2][16];
    const float* xb = x + (size_t)batch * CHW + posw + cl;
#pragma unroll
    for (int s = 0; s < 2; ++s)
#pragma unroll
        for (int j = 0; j < 8; ++j) {
            xs[s][j]     = xb[(size_t)(d0 + j) * HW + 16 * s];
            xs[s][j + 8] = xb[(size_t)(32 + d0 + j) * HW + 16 * s];
        }

    bf16x8 af[2][2];
#pragma unroll
    for (int s = 0; s < 2; ++s)
#pragma unroll
        for (int h = 0; h < 2; ++h)
#pragma unroll
            for (int i = 0; i < 8; ++i)
                af[s][h][i] = (short)f2bf(xs[s][8 * h + i]);

    // ---- score loop: 32 col-tiles of 16 codes ----
    float best[2][4]; int bidx[2][4];
#pragma unroll
    for (int s = 0; s < 2; ++s)
#pragma unroll
        for (int i = 0; i < 4; ++i) { best[s][i] = -1e30f; bidx[s][i] = 0; }

    const char* wlb = (const char*)wl;
#pragma unroll 4
    for (int tt = 0; tt < 32; ++tt) {
        int c  = (tt << 4) + cl;
        int rb = c << 7;
        int sw = (c & 7) << 4;
        bf16x8 b0 = *(const bf16x8*)(wlb + (rb | ((16 * g) ^ sw)));
        bf16x8 b1 = *(const bf16x8*)(wlb + (rb | ((64 + 16 * g) ^ sw)));
        float bs = biasl[c];
#pragma unroll
        for (int s = 0; s < 2; ++s) {
            f32x4 acc = {bs, bs, bs, bs};
            acc = __builtin_amdgcn_mfma_f32_16x16x32_bf16(af[s][0], b0, acc, 0, 0, 0);
            acc = __builtin_amdgcn_mfma_f32_16x16x32_bf16(af[s][1], b1, acc, 0, 0, 0);
#pragma unroll
            for (int i = 0; i < 4; ++i)
                if (acc[i] > best[s][i]) { best[s][i] = acc[i]; bidx[s][i] = c; }
        }
    }

    // ---- 16-lane butterfly argmax (tie -> smaller index) ----
#pragma unroll
    for (int s = 0; s < 2; ++s)
#pragma unroll
        for (int i = 0; i < 4; ++i) {
            float bd = best[s][i]; int bi = bidx[s][i];
#pragma unroll
            for (int off = 1; off < 16; off <<= 1) {
                float od = __shfl_xor(bd, off, 64);
                int   oi = __shfl_xor(bi, off, 64);
                if (od > bd || (od == bd && oi < bi)) { bd = od; bi = oi; }
            }
            bidx[s][i] = bi;
        }

    // winners to LDS (row-in-wave = 16s + 4g + i), + histogram
    if (cl == 0) {
#pragma unroll
        for (int s = 0; s < 2; ++s)
#pragma unroll
            for (int i = 0; i < 4; ++i) {
                int w = bidx[s][i];
                winners[(wv << 5) + (s << 4) + (g << 2) + i] = w;
                atomicAdd(&hc[w], 1);
            }
    }
    __syncthreads();   // hc complete across waves

    // ---- counts + loss flushed early (atomics off the tail) ----
    // loss needs ls first: compute quantized_st + loss now.
    float* outb = out + QOFF + (size_t)batch * CHW + posw + cl;
    float ls = 0.f;
#pragma unroll
    for (int s = 0; s < 2; ++s) {
        int widx = winners[(wv << 5) + (s << 4) + cl];
        float q[16];
        *(float4*)&q[0]  = *(const float4*)(wt + widx * 64 + d0);
        *(float4*)&q[4]  = *(const float4*)(wt + widx * 64 + d0 + 4);
        *(float4*)&q[8]  = *(const float4*)(wt + widx * 64 + 32 + d0);
        *(float4*)&q[12] = *(const float4*)(wt + widx * 64 + 32 + d0 + 4);
#pragma unroll
        for (int j = 0; j < 8; ++j) {
            float da = q[j]     - xs[s][j];
            float db = q[j + 8] - xs[s][j + 8];
            ls += da * da + db * db;
            __builtin_nontemporal_store(xs[s][j]     + da, &outb[(size_t)(d0 + j) * HW + 16 * s]);
            __builtin_nontemporal_store(xs[s][j + 8] + db, &outb[(size_t)(32 + d0 + j) * HW + 16 * s]);
        }
    }

    // loss reduction
    double lsd = (double)ls;
    for (int off = 32; off; off >>= 1) lsd += __shfl_down(lsd, off, 64);
    if (l == 0) lred[wv] = lsd;
    __syncthreads();
    if (t == 0) {
        double s = 0.0;
#pragma unroll
        for (int i = 0; i < 8; ++i) s += lred[i];
        atomicAdd(loss_acc, s);
    }
    int v0 = hc[t];
    if (v0) atomicAdd(&counts[t], v0);

    // ---- one-hot full rows: pure NT store drain to endpgm ----
    // wave-local: 32 rows x 512 floats, f32x2 stores (region 8B-aligned)
    {
        f32x2* encp = (f32x2*)(out + ENCOFF);
        size_t rowq = ((size_t)batch * 4096 + posw) * 256;   // f32x2 units
#pragma unroll 4
        for (int r = 0; r < 32; ++r, rowq += 256) {
            int id = winners[(wv << 5) + r];
#pragma unroll
            for (int p = 0; p < 4; ++p) {
                int k = (l + (p << 6)) << 1;
                f32x2 v;
                v.x = (k == id)     ? 1.f : 0.f;
                v.y = (k + 1 == id) ? 1.f : 0.f;
                __builtin_nontemporal_store(v, &encp[rowq + l + (p << 6)]);
            }
        }
    }
}

__global__ __launch_bounds__(512) void vq_fin(const int* __restrict__ counts,
                                              const double* __restrict__ loss_acc,
                                              float* __restrict__ out) {
    __shared__ double red[512];
    int k = threadIdx.x;
    double p = (double)counts[k] * (1.0 / 131072.0);
    red[k] = p * log(p + 1e-10);
    __syncthreads();
    for (int s = 256; s; s >>= 1) {
        if (k < s) red[k] += red[k + s];
        __syncthreads();
    }
    if (k == 0) {
        out[PERPOFF] = (float)exp(-red[0]);
        out[0] = (float)(loss_acc[0] * 1.25 / 8388608.0);
    }
}

extern "C" void kernel_launch(void* const* d_in, const int* in_sizes, int n_in,
                              void* d_out, int out_size, void* d_ws, size_t ws_size,
                              hipStream_t stream) {
    const float* x  = (const float*)d_in[0];
    const float* wt = (const float*)d_in[1];
    float* out = (float*)d_out;
    char* ws = (char*)d_ws;

    int*            counts = (int*)ws;
    double*         loss   = (double*)(ws + 2048);
    float*          bias   = (float*)(ws + 4096);
    unsigned short* wbf    = (unsigned short*)(ws + 8192);

    vq_prep<<<512, 64, 0, stream>>>(wt, bias, wbf, counts, loss);
    vq_assign<<<512, 512, 0, stream>>>(x, wt, bias, wbf, out, counts, loss);
    vq_fin<<<1, 512, 0, stream>>>(counts, loss, out);
}

// Round 9
// 97.602 us; speedup vs baseline: 1.3703x; 1.3703x over previous
//
#include <hip/hip_runtime.h>

typedef short   bf16x8 __attribute__((ext_vector_type(8)));
typedef float   f32x4  __attribute__((ext_vector_type(4)));
typedef float   f32x2  __attribute__((ext_vector_type(2)));

#define NVEC   131072      // 32*64*64 vectors
#define HW     4096
#define CHW    262144
#define QOFF   1
#define PERPOFF 8388609
#define ENCOFF  8388610

// ws layout: counts[512] @0, double loss @2048, float bias[512] @4096,
//            ushort wbf[512*64] @8192 (64 KB), int idx[131072] @73728

__device__ inline unsigned short f2bf(float f) {   // RTNE float->bf16
    unsigned int u = __float_as_uint(f);
    u += 0x7fffu + ((u >> 16) & 1u);
    return (unsigned short)(u >> 16);
}

// per code: bf16 copy of W + bias = -0.5*||w||^2 (f32-exact).
// Block 0 additionally zeroes counts + loss.
__global__ __launch_bounds__(64) void vq_prep(const float* __restrict__ wt,
                                              float* __restrict__ bias,
                                              unsigned short* __restrict__ wbf,
                                              int* __restrict__ counts,
                                              double* __restrict__ loss) {
    int c = blockIdx.x, d = threadIdx.x;
    if (c == 0) {
#pragma unroll
        for (int i = 0; i < 8; ++i) counts[d * 8 + i] = 0;
        if (d == 0) loss[0] = 0.0;
    }
    float v = wt[c * 64 + d];
    wbf[c * 64 + d] = f2bf(v);
    float s = v * v;
    for (int off = 32; off; off >>= 1) s += __shfl_down(s, off, 64);
    if (d == 0) bias[c] = -0.5f * s;
}

// 512 blocks x 512 threads (8 waves). Wave handles 32 rows.
// Scores via mfma_f32_16x16x32_bf16 (C = -wsq/2); argmax; then quantized_st
// routed through an LDS transpose (reusing the W tile) so out stores are
// 256B-contiguous per instruction instead of 4x64B scatters.
__global__ __launch_bounds__(512) void vq_assign(
    const float* __restrict__ x, const float* __restrict__ wt,
    const float* __restrict__ bias, const unsigned short* __restrict__ wbf,
    float* __restrict__ out, int* __restrict__ idx,
    int* __restrict__ counts, double* __restrict__ loss_acc)
{
    __shared__ ulonglong2 smem[4096];         // 64 KB: W tile, then f32 transpose
    __shared__ float  biasl[512];
    __shared__ int    hc[512];
    __shared__ int    winners[256];
    __shared__ double lred[8];

    unsigned short* wl    = (unsigned short*)smem;
    float*          trans = (float*)smem;     // 256 rows x 64 f32 (post-score)

    const int t = threadIdx.x, b = blockIdx.x;
    const int batch  = b >> 4;
    const int posblk = (b & 15) << 8;

    const int wv = t >> 6, l = t & 63;
    const int g  = l >> 4, cl = l & 15;
    const int posw = posblk + (wv << 5);      // this wave's 32 pos
    const int d0 = g << 3;

    // ---- issue W staging loads FIRST (so ds_writes wait only on these) ----
    ulonglong2 stg[8];
    {
        const ulonglong2* src = (const ulonglong2*)wbf;   // 16B units
#pragma unroll
        for (int i = 0; i < 8; ++i) stg[i] = src[t + 512 * i];
    }
    float bsl = bias[t];

    // ---- X loads (A-fragment layout), overlap with staging below ----
    float xs[2][16];
    const float* xb = x + (size_t)batch * CHW + posw + cl;
#pragma unroll
    for (int s = 0; s < 2; ++s)
#pragma unroll
        for (int j = 0; j < 8; ++j) {
            xs[s][j]     = xb[(size_t)(d0 + j) * HW + 16 * s];
            xs[s][j + 8] = xb[(size_t)(32 + d0 + j) * HW + 16 * s];
        }

    // ---- stage W bf16 into LDS with st-swizzle (row c: byte ^= (c&7)<<4) ----
#pragma unroll
    for (int i = 0; i < 8; ++i) {
        int u  = t + 512 * i;          // 16B-unit index, 0..4095
        int c  = u >> 3;               // code row
        int bo = (u & 7) << 4;         // byte-in-row
        *(ulonglong2*)((char*)wl + ((c << 7) | (bo ^ ((c & 7) << 4)))) = stg[i];
    }
    biasl[t] = bsl;
    hc[t] = 0;
    __syncthreads();

    bf16x8 af[2][2];
#pragma unroll
    for (int s = 0; s < 2; ++s)
#pragma unroll
        for (int h = 0; h < 2; ++h)
#pragma unroll
            for (int i = 0; i < 8; ++i)
                af[s][h][i] = (short)f2bf(xs[s][8 * h + i]);

    // ---- score loop: 32 col-tiles of 16 codes ----
    float best[2][4]; int bidx[2][4];
#pragma unroll
    for (int s = 0; s < 2; ++s)
#pragma unroll
        for (int i = 0; i < 4; ++i) { best[s][i] = -1e30f; bidx[s][i] = 0; }

    const char* wlb = (const char*)wl;
#pragma unroll 4
    for (int tt = 0; tt < 32; ++tt) {
        int c  = (tt << 4) + cl;
        int rb = c << 7;
        int sw = (c & 7) << 4;
        bf16x8 b0 = *(const bf16x8*)(wlb + (rb | ((16 * g) ^ sw)));
        bf16x8 b1 = *(const bf16x8*)(wlb + (rb | ((64 + 16 * g) ^ sw)));
        float bs = biasl[c];
#pragma unroll
        for (int s = 0; s < 2; ++s) {
            f32x4 acc = {bs, bs, bs, bs};
            acc = __builtin_amdgcn_mfma_f32_16x16x32_bf16(af[s][0], b0, acc, 0, 0, 0);
            acc = __builtin_amdgcn_mfma_f32_16x16x32_bf16(af[s][1], b1, acc, 0, 0, 0);
#pragma unroll
            for (int i = 0; i < 4; ++i)
                if (acc[i] > best[s][i]) { best[s][i] = acc[i]; bidx[s][i] = c; }
        }
    }

    // ---- 16-lane butterfly argmax (tie -> smaller index) ----
#pragma unroll
    for (int s = 0; s < 2; ++s)
#pragma unroll
        for (int i = 0; i < 4; ++i) {
            float bd = best[s][i]; int bi = bidx[s][i];
#pragma unroll
            for (int off = 1; off < 16; off <<= 1) {
                float od = __shfl_xor(bd, off, 64);
                int   oi = __shfl_xor(bi, off, 64);
                if (od > bd || (od == bd && oi < bi)) { bd = od; bi = oi; }
            }
            bidx[s][i] = bi;
        }

    // winners to LDS (row-in-wave = 16s + 4g + i), + histogram
    if (cl == 0) {
#pragma unroll
        for (int s = 0; s < 2; ++s)
#pragma unroll
            for (int i = 0; i < 4; ++i) {
                int w = bidx[s][i];
                winners[(wv << 5) + (s << 4) + (g << 2) + i] = w;
                atomicAdd(&hc[w], 1);
            }
    }
    __syncthreads();   // winners+hc complete; wl (W tile) now dead

    // compact index write + counts (atomics flow early)
    if (t < 256)
        idx[(size_t)batch * 4096 + posblk + t] = winners[t];
    {
        int v0 = hc[t];
        if (v0) atomicAdd(&counts[t], v0);
    }

    // ---- epilogue: quantized_st + loss (f32-exact), values -> swizzled trans ----
    float ls = 0.f;
#pragma unroll
    for (int s = 0; s < 2; ++s) {
        int r  = (wv << 5) + (s << 4) + cl;   // local row 0..255
        int rb = r << 6;                       // dword base
        int m  = r & 31;
        int widx = winners[r];
        float q[16];
        *(float4*)&q[0]  = *(const float4*)(wt + widx * 64 + d0);
        *(float4*)&q[4]  = *(const float4*)(wt + widx * 64 + d0 + 4);
        *(float4*)&q[8]  = *(const float4*)(wt + widx * 64 + 32 + d0);
        *(float4*)&q[12] = *(const float4*)(wt + widx * 64 + 32 + d0 + 4);
#pragma unroll
        for (int j = 0; j < 8; ++j) {
            float da = q[j]     - xs[s][j];
            float db = q[j + 8] - xs[s][j + 8];
            ls += da * da + db * db;
            int d1 = d0 + j, d2 = 32 + d0 + j;
            trans[rb + (d1 ^ m)] = xs[s][j]     + da;
            trans[rb + (d2 ^ m)] = xs[s][j + 8] + db;
        }
    }

    // loss partial to LDS
    double lsd = (double)ls;
    for (int off = 32; off; off >>= 1) lsd += __shfl_down(lsd, off, 64);
    if (l == 0) lred[wv] = lsd;
    __syncthreads();   // trans + lred ready
    if (t == 0) {
        double s = 0.0;
#pragma unroll
        for (int i = 0; i < 8; ++i) s += lred[i];
        atomicAdd(loss_acc, s);
    }

    // ---- out stores: 256B-contiguous per instruction ----
    // wave wv covers d = wv*8 .. wv*8+7, all 256 pos
    {
        float* outp = out + QOFF + (size_t)batch * CHW + posblk;
#pragma unroll
        for (int dd = 0; dd < 8; ++dd) {
            int d = (wv << 3) + dd;
#pragma unroll
            for (int q4 = 0; q4 < 4; ++q4) {
                int pos = (q4 << 6) + l;
                outp[(size_t)d * HW + pos] = trans[(pos << 6) + (d ^ (pos & 31))];
            }
        }
    }
}

// One-hot expansion: each line written exactly once, nontemporal.
__global__ __launch_bounds__(256) void vq_enc(const int* __restrict__ idx,
                                              f32x2* __restrict__ enc) {
    int gid = blockIdx.x * 256 + threadIdx.x;   // 33,554,432 threads
    int row = gid >> 8;                          // 256 f32x2 per row
    int pos = (gid & 255) << 1;
    int id = idx[row];
    f32x2 v;
    v.x = (id == pos)     ? 1.f : 0.f;
    v.y = (id == pos + 1) ? 1.f : 0.f;
    __builtin_nontemporal_store(v, &enc[gid]);
}

__global__ __launch_bounds__(512) void vq_fin(const int* __restrict__ counts,
                                              const double* __restrict__ loss_acc,
                                              float* __restrict__ out) {
    __shared__ double red[512];
    int k = threadIdx.x;
    double p = (double)counts[k] * (1.0 / 131072.0);
    red[k] = p * log(p + 1e-10);
    __syncthreads();
    for (int s = 256; s; s >>= 1) {
        if (k < s) red[k] += red[k + s];
        __syncthreads();
    }
    if (k == 0) {
        out[PERPOFF] = (float)exp(-red[0]);
        out[0] = (float)(loss_acc[0] * 1.25 / 8388608.0);
    }
}

extern "C" void kernel_launch(void* const* d_in, const int* in_sizes, int n_in,
                              void* d_out, int out_size, void* d_ws, size_t ws_size,
                              hipStream_t stream) {
    const float* x  = (const float*)d_in[0];
    const float* wt = (const float*)d_in[1];
    float* out = (float*)d_out;
    char* ws = (char*)d_ws;

    int*            counts = (int*)ws;
    double*         loss   = (double*)(ws + 2048);
    float*          bias   = (float*)(ws + 4096);
    unsigned short* wbf    = (unsigned short*)(ws + 8192);
    int*            idx    = (int*)(ws + 73728);
    float*          enc    = out + ENCOFF;

    vq_prep<<<512, 64, 0, stream>>>(wt, bias, wbf, counts, loss);
    vq_assign<<<512, 512, 0, stream>>>(x, wt, bias, wbf, out, idx, counts, loss);
    vq_enc<<<131072, 256, 0, stream>>>(idx, (f32x2*)enc);
    vq_fin<<<1, 512, 0, stream>>>(counts, loss, out);
}